// Round 1
// baseline (366.966 us; speedup 1.0000x reference)
//
#include <hip/hip_runtime.h>
#include <cstdint>

// ChessGNN forward, MI355X. All f32.
// B=2048 graphs, N=90 nodes, C=64 channels, 4 heads x 16.
// Pipeline: gat0 -> stats0 -> gat1 (in-place) -> stats1 -> final.
// ws usage: outPre (B*N*C) + partial (B*C) + partialSq (B*C) + st0(128) + st1(128)
//   = 12,058,880 floats = ~46 MB.

#define BB   2048
#define NN   90
#define CC   64
#define NH   4
#define HD   16
#define TPB  512
#define DOUT 128

// ---------------------------------------------------------------- GAT layer
// LAYER==0: x = concat(board,pos) @ in_W + in_b
// LAYER==1: x = relu(prevPre * s + t)   (fused BN apply)
template <int LAYER>
__global__ __launch_bounds__(TPB) void k_gat(
    const float* __restrict__ bp,       // (B,14,90)   [layer0]
    const float* __restrict__ inW,      // (16,64)     [layer0]
    const float* __restrict__ inb,      // (64)        [layer0]
    const float* __restrict__ prevPre,  // (B,N,C)     [layer1]
    const float* __restrict__ stPrev,   // (2*C) s,t   [layer1]
    const float* __restrict__ Wl,       // (64,64)
    const float* __restrict__ asrc,     // (4,16)
    const float* __restrict__ adst,     // (4,16)
    float* __restrict__ outPre,         // (B,N,C) pre-BN out
    float* __restrict__ partial,        // (B,C) sum
    float* __restrict__ partialSq)      // (B,C) sumsq
{
    __shared__ float sW[CC * CC];          // 16 KB
    __shared__ float sx[NN][CC];           // 23 KB
    __shared__ float sh[NN][CC];           // 23 KB
    __shared__ float sAs[NH * HD], sAd[NH * HD];
    __shared__ float sSrc[NH][NN], sDst[NH][NN];
    __shared__ float sP[NH][NN][20];       // 28.8 KB softmax probs (neighbor-compressed)
    __shared__ unsigned char sNbr[NN][20]; // neighbor indices
    __shared__ unsigned char sCnt[NN];
    __shared__ float sRed[TPB];
    __shared__ float sInW[16 * CC];        // layer0 only
    __shared__ float sInb[CC];
    __shared__ float sXr[NN][16];
    __shared__ float sST[2 * CC];          // layer1 only

    const int b = blockIdx.x, t = threadIdx.x;

    for (int i = t; i < CC * CC; i += TPB) sW[i] = Wl[i];
    if (t < NH * HD) { sAs[t] = asrc[t]; sAd[t] = adst[t]; }

    if (LAYER == 0) {
        for (int i = t; i < 16 * CC; i += TPB) sInW[i] = inW[i];
        if (t < CC) sInb[t] = inb[t];
        const float* bpb = bp + (size_t)b * (14 * NN);
        for (int i = t; i < 14 * NN; i += TPB) {
            int p = i / NN, n = i - p * NN;
            sXr[n][p] = bpb[i];
        }
        if (t < NN) {
            int y = t / 9, x = t - y * 9;
            sXr[t][14] = (float)x / 9.0f;
            sXr[t][15] = (float)y / 10.0f;
        }
    } else {
        if (t < 2 * CC) sST[t] = stPrev[t];
    }

    // neighbor lists: (y,x) ~ same row |dx|<=4, same col |dy|<=5, incl self
    if (t < NN) {
        int y = t / 9, x = t - y * 9;
        int cnt = 0;
        int x0 = x - 4; if (x0 < 0) x0 = 0;
        int x1 = x + 4; if (x1 > 8) x1 = 8;
        for (int xx = x0; xx <= x1; xx++) sNbr[t][cnt++] = (unsigned char)(y * 9 + xx);
        int y0 = y - 5; if (y0 < 0) y0 = 0;
        int y1 = y + 5; if (y1 > 9) y1 = 9;
        for (int yy = y0; yy <= y1; yy++)
            if (yy != y) sNbr[t][cnt++] = (unsigned char)(yy * 9 + x);
        sCnt[t] = (unsigned char)cnt;
    }
    __syncthreads();

    // ---- input transform into sx
    if (LAYER == 0) {
        for (int i = t; i < NN * CC; i += TPB) {
            int n = i >> 6, c = i & 63;
            float a = sInb[c];
            #pragma unroll
            for (int p = 0; p < 16; p++) a = fmaf(sXr[n][p], sInW[p * CC + c], a);
            sx[n][c] = a;
        }
    } else {
        const float* pv = prevPre + (size_t)b * (NN * CC);
        for (int i = t; i < NN * CC; i += TPB) {
            int c = i & 63;
            float v = fmaf(pv[i], sST[c], sST[CC + c]);
            sx[i >> 6][c] = v > 0.0f ? v : 0.0f;
        }
    }
    __syncthreads();

    // ---- h = x @ W  (90x64 @ 64x64), float4 over k on the x side
    for (int i = t; i < NN * CC; i += TPB) {
        int n = i >> 6, c = i & 63;
        const float4* xr = reinterpret_cast<const float4*>(&sx[n][0]);
        float a = 0.0f;
        #pragma unroll
        for (int k4 = 0; k4 < CC / 4; k4++) {
            float4 xv = xr[k4];
            int k = 4 * k4;
            a = fmaf(xv.x, sW[(k + 0) * CC + c], a);
            a = fmaf(xv.y, sW[(k + 1) * CC + c], a);
            a = fmaf(xv.z, sW[(k + 2) * CC + c], a);
            a = fmaf(xv.w, sW[(k + 3) * CC + c], a);
        }
        sh[n][c] = a;
    }
    __syncthreads();

    // ---- attention scores per (head, node)
    for (int i = t; i < NH * NN; i += TPB) {
        int hh = i / NN, n = i - hh * NN;
        float a = 0.0f, d = 0.0f;
        #pragma unroll
        for (int k = 0; k < HD; k++) {
            float v = sh[n][hh * HD + k];
            a = fmaf(v, sAs[hh * HD + k], a);
            d = fmaf(v, sAd[hh * HD + k], d);
        }
        sSrc[hh][n] = a; sDst[hh][n] = d;
    }
    __syncthreads();

    // ---- masked softmax over neighbor list (self always present -> no NaN)
    for (int i = t; i < NH * NN; i += TPB) {
        int hh = i / NN, n = i - hh * NN;
        float si = sSrc[hh][n];
        int cnt = sCnt[n];
        float m = -1e30f;
        for (int k = 0; k < cnt; k++) {
            int j = sNbr[n][k];
            float e = si + sDst[hh][j];
            e = e > 0.0f ? e : 0.2f * e;
            m = fmaxf(m, e);
        }
        float s = 0.0f;
        for (int k = 0; k < cnt; k++) {
            int j = sNbr[n][k];
            float e = si + sDst[hh][j];
            e = e > 0.0f ? e : 0.2f * e;
            float p = __expf(e - m);
            sP[hh][n][k] = p;
            s += p;
        }
        float inv = 1.0f / s;
        for (int k = 0; k < cnt; k++) sP[hh][n][k] *= inv;
    }
    __syncthreads();

    // ---- out = attn @ h  over neighbors; write global + BN partials
    float lsum = 0.0f, lsq = 0.0f;
    const int c = t & 63;          // channel is fixed per thread (TPB % 64 == 0)
    const int hh = c >> 4;
    float* op = outPre + (size_t)b * (NN * CC);
    for (int i = t; i < NN * CC; i += TPB) {
        int n = i >> 6;
        int cnt = sCnt[n];
        float a = 0.0f;
        for (int k = 0; k < cnt; k++) {
            int j = sNbr[n][k];
            a = fmaf(sP[hh][n][k], sh[j][c], a);
        }
        op[i] = a;
        lsum += a;
        lsq = fmaf(a, a, lsq);
    }
    sRed[t] = lsum;
    __syncthreads();
    if (t < CC) {
        float s = 0.0f;
        #pragma unroll
        for (int k = 0; k < TPB / CC; k++) s += sRed[t + k * CC];
        partial[(size_t)b * CC + t] = s;
    }
    __syncthreads();
    sRed[t] = lsq;
    __syncthreads();
    if (t < CC) {
        float s = 0.0f;
        #pragma unroll
        for (int k = 0; k < TPB / CC; k++) s += sRed[t + k * CC];
        partialSq[(size_t)b * CC + t] = s;
    }
}

// ------------------------------------------------------------- BN statistics
// grid = 64 (one block per channel). st[c] = gamma*rsqrt(var+eps),
// st[64+c] = beta - mean*st[c]
__global__ __launch_bounds__(256) void k_stats(
    const float* __restrict__ partial, const float* __restrict__ partialSq,
    const float* __restrict__ gamma, const float* __restrict__ beta,
    float* __restrict__ st)
{
    const int c = blockIdx.x, t = threadIdx.x;
    float s = 0.0f, q = 0.0f;
    for (int b = t; b < BB; b += 256) {
        s += partial[(size_t)b * CC + c];
        q += partialSq[(size_t)b * CC + c];
    }
    __shared__ float rs[256], rq[256];
    rs[t] = s; rq[t] = q;
    __syncthreads();
    for (int o = 128; o > 0; o >>= 1) {
        if (t < o) { rs[t] += rs[t + o]; rq[t] += rq[t + o]; }
        __syncthreads();
    }
    if (t == 0) {
        const float cntInv = 1.0f / (float)(BB * NN);
        float mean = rs[0] * cntInv;
        float var  = rq[0] * cntInv - mean * mean;
        float sc = gamma[c] * rsqrtf(var + 1e-5f);
        st[c] = sc;
        st[CC + c] = beta[c] - mean * sc;
    }
}

// ------------------------------------------------------------------- final
// BN+relu, mean over nodes, @ out_W + out_b
__global__ __launch_bounds__(DOUT) void k_final(
    const float* __restrict__ pre, const float* __restrict__ st,
    const float* __restrict__ outW, const float* __restrict__ outb,
    float* __restrict__ out)
{
    const int b = blockIdx.x, t = threadIdx.x;
    __shared__ float m[CC];
    const float* pv = pre + (size_t)b * (NN * CC);
    if (t < CC) {
        float s = st[t], sh = st[CC + t], a = 0.0f;
        for (int n = 0; n < NN; n++) {
            float v = fmaf(pv[n * CC + t], s, sh);
            a += (v > 0.0f ? v : 0.0f);
        }
        m[t] = a * (1.0f / (float)NN);
    }
    __syncthreads();
    float a = outb[t];
    #pragma unroll
    for (int c = 0; c < CC; c++) a = fmaf(m[c], outW[c * DOUT + t], a);
    out[(size_t)b * DOUT + t] = a;
}

// ------------------------------------------------------------------ launch
extern "C" void kernel_launch(void* const* d_in, const int* in_sizes, int n_in,
                              void* d_out, int out_size, void* d_ws, size_t ws_size,
                              hipStream_t stream) {
    (void)in_sizes; (void)n_in; (void)out_size; (void)ws_size;

    const float* bp   = (const float*)d_in[0];   // (2048,14,10,9)
    const float* inW  = (const float*)d_in[1];   // (16,64)
    const float* inb  = (const float*)d_in[2];   // (64)
    const float* W0   = (const float*)d_in[3];   // (64,64)
    const float* as0  = (const float*)d_in[4];   // (4,16)
    const float* ad0  = (const float*)d_in[5];
    const float* g0   = (const float*)d_in[6];
    const float* b0   = (const float*)d_in[7];
    const float* W1   = (const float*)d_in[8];
    const float* as1  = (const float*)d_in[9];
    const float* ad1  = (const float*)d_in[10];
    const float* g1   = (const float*)d_in[11];
    const float* b1   = (const float*)d_in[12];
    const float* outW = (const float*)d_in[13];  // (64,128)
    const float* outb = (const float*)d_in[14];  // (128)
    float* out = (float*)d_out;                  // (2048,128)

    float* ws = (float*)d_ws;
    float* outPre    = ws;                               // B*N*C
    float* partial   = outPre + (size_t)BB * NN * CC;    // B*C
    float* partialSq = partial + (size_t)BB * CC;        // B*C
    float* st0       = partialSq + (size_t)BB * CC;      // 2*C
    float* st1       = st0 + 2 * CC;                     // 2*C

    k_gat<0><<<BB, TPB, 0, stream>>>(bp, inW, inb, nullptr, nullptr,
                                     W0, as0, ad0, outPre, partial, partialSq);
    k_stats<<<CC, 256, 0, stream>>>(partial, partialSq, g0, b0, st0);
    k_gat<1><<<BB, TPB, 0, stream>>>(nullptr, nullptr, nullptr, outPre, st0,
                                     W1, as1, ad1, outPre, partial, partialSq);
    k_stats<<<CC, 256, 0, stream>>>(partial, partialSq, g1, b1, st1);
    k_final<<<BB, DOUT, 0, stream>>>(outPre, st1, outW, outb, out);
}

// Round 2
// 200.795 us; speedup vs baseline: 1.8276x; 1.8276x over previous
//
#include <hip/hip_runtime.h>
#include <cstdint>

// ChessGNN forward, MI355X. All f32.
// B=2048 graphs, N=90 nodes, C=64 channels, 4 heads x 16.
// R1: LDS aliased to ~80KB (2 blocks/CU), register-tiled (4c x 3n per thread)
// matmul + aggregation with b128 LDS reads.

#define BB   2048
#define NN   90
#define CC   64
#define NH   4
#define HD   16
#define TPB  512
#define DOUT 128
#define XPAD 65      // sx row pad (bank spread, scalar reads)
#define HPAD 68      // sh row pad (16B-aligned rows for float4 reads)
#define MAXNBR 18

// union region offsets (bytes)
//  phase 1-3: sW[0..16384) + sInW[16384..20480) + sInb[20480..20736) + sXr[20736..26856)
//  phase 5-6: sP [4][90][18] f32 = 25920 B at 0
//  phase 7:   sRa[32][64] at 0, sRb[32][64] at 8192
#define UNI_BYTES 26880

template <int LAYER>
__global__ __launch_bounds__(TPB, 4) void k_gat(
    const float* __restrict__ bp,       // (B,14,90)   [layer0]
    const float* __restrict__ inW,      // (16,64)     [layer0]
    const float* __restrict__ inb,      // (64)        [layer0]
    const float* __restrict__ prevPre,  // (B,N,C)     [layer1]
    const float* __restrict__ stPrev,   // (2*C) s,t   [layer1]
    const float* __restrict__ Wl,       // (64,64)
    const float* __restrict__ asrc,     // (4,16)
    const float* __restrict__ adst,     // (4,16)
    float* __restrict__ outPre,         // (B,N,C) pre-BN out
    float* __restrict__ partial,        // (B,C) sum
    float* __restrict__ partialSq)      // (B,C) sumsq
{
    __shared__ __align__(16) unsigned char uni[UNI_BYTES];
    __shared__ __align__(16) float sx[NN][XPAD];
    __shared__ __align__(16) float sh[NN][HPAD];
    __shared__ float sAs[NH * HD], sAd[NH * HD];
    __shared__ float sSrc[NH][NN], sDst[NH][NN];
    __shared__ unsigned char sNbr[NN][MAXNBR];
    __shared__ unsigned char sCnt[NN];
    __shared__ float sST[2 * CC];

    float* sW   = (float*)uni;                  // 64x64
    float* sInW = (float*)(uni + 16384);        // 16x64
    float* sInb = (float*)(uni + 20480);        // 64
    float* sXr  = (float*)(uni + 20736);        // [90][17]
    float* sP   = (float*)uni;                  // [4][90][18]
    float* sRa  = (float*)uni;                  // [32][64]
    float* sRb  = (float*)(uni + 8192);         // [32][64]

    const int b = blockIdx.x, t = threadIdx.x;
    const int cq = t & 15, ng = t >> 4;         // c-quad 0..15, n-group 0..31
    const int c4 = cq << 2;
    const int jcnt = (ng < NN - 64) ? 3 : 2;    // rows per thread (ng, ng+32, ng+64)

    // ---------------- phase 1: stage weights / inputs / neighbor lists
    for (int i = t; i < CC * CC; i += TPB) sW[i] = Wl[i];
    if (t < NH * HD) { sAs[t] = asrc[t]; sAd[t] = adst[t]; }

    if (LAYER == 0) {
        for (int i = t; i < 16 * CC; i += TPB) sInW[i] = inW[i];
        if (t < CC) sInb[t] = inb[t];
        const float* bpb = bp + (size_t)b * (14 * NN);
        for (int i = t; i < 14 * NN; i += TPB) {
            int p = i / NN, n = i - p * NN;
            sXr[n * 17 + p] = bpb[i];
        }
        if (t < NN) {
            int y = t / 9, x = t - y * 9;
            sXr[t * 17 + 14] = (float)x / 9.0f;
            sXr[t * 17 + 15] = (float)y / 10.0f;
        }
    } else {
        if (t < 2 * CC) sST[t] = stPrev[t];
    }

    if (t < NN) {
        int y = t / 9, x = t - y * 9;
        int cnt = 0;
        int x0 = x - 4; if (x0 < 0) x0 = 0;
        int x1 = x + 4; if (x1 > 8) x1 = 8;
        for (int xx = x0; xx <= x1; xx++) sNbr[t][cnt++] = (unsigned char)(y * 9 + xx);
        int y0 = y - 5; if (y0 < 0) y0 = 0;
        int y1 = y + 5; if (y1 > 9) y1 = 9;
        for (int yy = y0; yy <= y1; yy++)
            if (yy != y) sNbr[t][cnt++] = (unsigned char)(yy * 9 + x);
        sCnt[t] = (unsigned char)cnt;
    }
    __syncthreads();

    // ---------------- phase 2: x (input proj / BN-apply+relu) -> sx
    if (LAYER == 0) {
        const int n0 = ng, n1 = ng + 32, n2 = (jcnt == 3) ? ng + 64 : ng;
        float acc[3][4] = {};
        #pragma unroll
        for (int k = 0; k < 16; k++) {
            float4 w = *(const float4*)&sInW[k * CC + c4];
            float x0 = sXr[n0 * 17 + k], x1 = sXr[n1 * 17 + k], x2 = sXr[n2 * 17 + k];
            acc[0][0] = fmaf(x0, w.x, acc[0][0]); acc[0][1] = fmaf(x0, w.y, acc[0][1]);
            acc[0][2] = fmaf(x0, w.z, acc[0][2]); acc[0][3] = fmaf(x0, w.w, acc[0][3]);
            acc[1][0] = fmaf(x1, w.x, acc[1][0]); acc[1][1] = fmaf(x1, w.y, acc[1][1]);
            acc[1][2] = fmaf(x1, w.z, acc[1][2]); acc[1][3] = fmaf(x1, w.w, acc[1][3]);
            acc[2][0] = fmaf(x2, w.x, acc[2][0]); acc[2][1] = fmaf(x2, w.y, acc[2][1]);
            acc[2][2] = fmaf(x2, w.z, acc[2][2]); acc[2][3] = fmaf(x2, w.w, acc[2][3]);
        }
        for (int j = 0; j < jcnt; j++) {
            int n = ng + 32 * j;
            #pragma unroll
            for (int q = 0; q < 4; q++) sx[n][c4 + q] = acc[j][q] + sInb[c4 + q];
        }
    } else {
        const float4* pv4 = (const float4*)(prevPre + (size_t)b * (NN * CC));
        for (int i4 = t; i4 < NN * CC / 4; i4 += TPB) {
            float4 v = pv4[i4];
            int n = i4 >> 4, c = (i4 & 15) << 2;
            float a0 = fmaf(v.x, sST[c + 0], sST[CC + c + 0]);
            float a1 = fmaf(v.y, sST[c + 1], sST[CC + c + 1]);
            float a2 = fmaf(v.z, sST[c + 2], sST[CC + c + 2]);
            float a3 = fmaf(v.w, sST[c + 3], sST[CC + c + 3]);
            sx[n][c + 0] = a0 > 0.0f ? a0 : 0.0f;
            sx[n][c + 1] = a1 > 0.0f ? a1 : 0.0f;
            sx[n][c + 2] = a2 > 0.0f ? a2 : 0.0f;
            sx[n][c + 3] = a3 > 0.0f ? a3 : 0.0f;
        }
    }
    __syncthreads();

    // ---------------- phase 3: h = x @ W -> sh (register-tiled 3n x 4c)
    {
        const int n0 = ng, n1 = ng + 32, n2 = (jcnt == 3) ? ng + 64 : ng;
        float acc[3][4] = {};
        #pragma unroll 4
        for (int k = 0; k < CC; k++) {
            float4 w = *(const float4*)&sW[k * CC + c4];
            float x0 = sx[n0][k], x1 = sx[n1][k], x2 = sx[n2][k];
            acc[0][0] = fmaf(x0, w.x, acc[0][0]); acc[0][1] = fmaf(x0, w.y, acc[0][1]);
            acc[0][2] = fmaf(x0, w.z, acc[0][2]); acc[0][3] = fmaf(x0, w.w, acc[0][3]);
            acc[1][0] = fmaf(x1, w.x, acc[1][0]); acc[1][1] = fmaf(x1, w.y, acc[1][1]);
            acc[1][2] = fmaf(x1, w.z, acc[1][2]); acc[1][3] = fmaf(x1, w.w, acc[1][3]);
            acc[2][0] = fmaf(x2, w.x, acc[2][0]); acc[2][1] = fmaf(x2, w.y, acc[2][1]);
            acc[2][2] = fmaf(x2, w.z, acc[2][2]); acc[2][3] = fmaf(x2, w.w, acc[2][3]);
        }
        for (int j = 0; j < jcnt; j++) {
            int n = ng + 32 * j;
            float4 o; o.x = acc[j][0]; o.y = acc[j][1]; o.z = acc[j][2]; o.w = acc[j][3];
            *(float4*)&sh[n][c4] = o;
        }
    }
    __syncthreads();

    // ---------------- phase 4: attention scores per (head, node)
    if (t < NH * NN) {
        int hh = t / NN, n = t - hh * NN;
        const float4* hv = (const float4*)&sh[n][hh * HD];
        float a = 0.0f, d = 0.0f;
        #pragma unroll
        for (int m = 0; m < 4; m++) {
            float4 h4 = hv[m];
            a = fmaf(h4.x, sAs[hh * HD + 4 * m + 0], a);
            a = fmaf(h4.y, sAs[hh * HD + 4 * m + 1], a);
            a = fmaf(h4.z, sAs[hh * HD + 4 * m + 2], a);
            a = fmaf(h4.w, sAs[hh * HD + 4 * m + 3], a);
            d = fmaf(h4.x, sAd[hh * HD + 4 * m + 0], d);
            d = fmaf(h4.y, sAd[hh * HD + 4 * m + 1], d);
            d = fmaf(h4.z, sAd[hh * HD + 4 * m + 2], d);
            d = fmaf(h4.w, sAd[hh * HD + 4 * m + 3], d);
        }
        sSrc[hh][n] = a; sDst[hh][n] = d;
    }
    __syncthreads();

    // ---------------- phase 5: masked softmax over neighbor list -> sP
    // (sW / layer-0 staging region is dead now; sP aliases it)
    if (t < NH * NN) {
        int hh = t / NN, n = t - hh * NN;
        float si = sSrc[hh][n];
        int cnt = sCnt[n];
        float* pr = &sP[(hh * NN + n) * MAXNBR];
        float m = -1e30f;
        for (int k = 0; k < cnt; k++) {
            int j = sNbr[n][k];
            float e = si + sDst[hh][j];
            e = e > 0.0f ? e : 0.2f * e;
            m = fmaxf(m, e);
        }
        float s = 0.0f;
        for (int k = 0; k < cnt; k++) {
            int j = sNbr[n][k];
            float e = si + sDst[hh][j];
            e = e > 0.0f ? e : 0.2f * e;
            float p = __expf(e - m);
            pr[k] = p;
            s += p;
        }
        float inv = 1.0f / s;
        for (int k = 0; k < cnt; k++) pr[k] *= inv;
    }
    __syncthreads();

    // ---------------- phase 6: out = attn @ h over neighbors (3n x 4c tiles)
    const int hh2 = c4 >> 4;
    float lsum[4] = {}, lsq[4] = {};
    float* op = outPre + (size_t)b * (NN * CC);
    for (int j = 0; j < jcnt; j++) {
        int n = ng + 32 * j;
        int cnt = sCnt[n];
        const float* pr = &sP[(hh2 * NN + n) * MAXNBR];
        const unsigned char* nb = &sNbr[n][0];
        float a0 = 0.0f, a1 = 0.0f, a2 = 0.0f, a3 = 0.0f;
        for (int k = 0; k < cnt; k++) {
            int jn = nb[k];
            float p = pr[k];
            float4 h4 = *(const float4*)&sh[jn][c4];
            a0 = fmaf(p, h4.x, a0); a1 = fmaf(p, h4.y, a1);
            a2 = fmaf(p, h4.z, a2); a3 = fmaf(p, h4.w, a3);
        }
        float4 o; o.x = a0; o.y = a1; o.z = a2; o.w = a3;
        *(float4*)&op[n * CC + c4] = o;
        lsum[0] += a0; lsum[1] += a1; lsum[2] += a2; lsum[3] += a3;
        lsq[0] = fmaf(a0, a0, lsq[0]); lsq[1] = fmaf(a1, a1, lsq[1]);
        lsq[2] = fmaf(a2, a2, lsq[2]); lsq[3] = fmaf(a3, a3, lsq[3]);
    }
    __syncthreads();   // sP dead beyond here

    // ---------------- phase 7: BN partial sums (per-channel over this block)
    #pragma unroll
    for (int q = 0; q < 4; q++) {
        sRa[ng * CC + c4 + q] = lsum[q];
        sRb[ng * CC + c4 + q] = lsq[q];
    }
    __syncthreads();
    if (t < CC) {
        float s = 0.0f, q2 = 0.0f;
        #pragma unroll
        for (int g = 0; g < 32; g++) {
            s  += sRa[g * CC + t];
            q2 += sRb[g * CC + t];
        }
        partial[(size_t)b * CC + t] = s;
        partialSq[(size_t)b * CC + t] = q2;
    }
}

// ------------------------------------------------------------- BN statistics
__global__ __launch_bounds__(256) void k_stats(
    const float* __restrict__ partial, const float* __restrict__ partialSq,
    const float* __restrict__ gamma, const float* __restrict__ beta,
    float* __restrict__ st)
{
    const int c = blockIdx.x, t = threadIdx.x;
    float s = 0.0f, q = 0.0f;
    for (int b = t; b < BB; b += 256) {
        s += partial[(size_t)b * CC + c];
        q += partialSq[(size_t)b * CC + c];
    }
    __shared__ float rs[256], rq[256];
    rs[t] = s; rq[t] = q;
    __syncthreads();
    for (int o = 128; o > 0; o >>= 1) {
        if (t < o) { rs[t] += rs[t + o]; rq[t] += rq[t + o]; }
        __syncthreads();
    }
    if (t == 0) {
        const float cntInv = 1.0f / (float)(BB * NN);
        float mean = rs[0] * cntInv;
        float var  = rq[0] * cntInv - mean * mean;
        float sc = gamma[c] * rsqrtf(var + 1e-5f);
        st[c] = sc;
        st[CC + c] = beta[c] - mean * sc;
    }
}

// ------------------------------------------------------------------- final
__global__ __launch_bounds__(256) void k_final(
    const float* __restrict__ pre, const float* __restrict__ st,
    const float* __restrict__ outW, const float* __restrict__ outb,
    float* __restrict__ out)
{
    __shared__ float sM[CC];
    __shared__ float sPart[4][CC];
    const int b = blockIdx.x, t = threadIdx.x;
    const int c = t & 63, p = t >> 6;
    const float* pv = pre + (size_t)b * (NN * CC);
    float s = st[c], sft = st[CC + c];
    float a = 0.0f;
    int nBeg = p * 23, nEnd = nBeg + 23 < NN ? nBeg + 23 : NN;
    for (int n = nBeg; n < nEnd; n++) {
        float v = fmaf(pv[n * CC + c], s, sft);
        a += (v > 0.0f ? v : 0.0f);
    }
    sPart[p][c] = a;
    __syncthreads();
    if (t < CC)
        sM[t] = (sPart[0][t] + sPart[1][t] + sPart[2][t] + sPart[3][t]) * (1.0f / (float)NN);
    __syncthreads();
    if (t < DOUT) {
        float acc = outb[t];
        #pragma unroll
        for (int cc2 = 0; cc2 < CC; cc2++) acc = fmaf(sM[cc2], outW[cc2 * DOUT + t], acc);
        out[(size_t)b * DOUT + t] = acc;
    }
}

// ------------------------------------------------------------------ launch
extern "C" void kernel_launch(void* const* d_in, const int* in_sizes, int n_in,
                              void* d_out, int out_size, void* d_ws, size_t ws_size,
                              hipStream_t stream) {
    (void)in_sizes; (void)n_in; (void)out_size; (void)ws_size;

    const float* bp   = (const float*)d_in[0];
    const float* inW  = (const float*)d_in[1];
    const float* inb  = (const float*)d_in[2];
    const float* W0   = (const float*)d_in[3];
    const float* as0  = (const float*)d_in[4];
    const float* ad0  = (const float*)d_in[5];
    const float* g0   = (const float*)d_in[6];
    const float* b0   = (const float*)d_in[7];
    const float* W1   = (const float*)d_in[8];
    const float* as1  = (const float*)d_in[9];
    const float* ad1  = (const float*)d_in[10];
    const float* g1   = (const float*)d_in[11];
    const float* b1   = (const float*)d_in[12];
    const float* outW = (const float*)d_in[13];
    const float* outb = (const float*)d_in[14];
    float* out = (float*)d_out;

    float* ws = (float*)d_ws;
    float* outPre    = ws;
    float* partial   = outPre + (size_t)BB * NN * CC;
    float* partialSq = partial + (size_t)BB * CC;
    float* st0       = partialSq + (size_t)BB * CC;
    float* st1       = st0 + 2 * CC;

    k_gat<0><<<BB, TPB, 0, stream>>>(bp, inW, inb, nullptr, nullptr,
                                     W0, as0, ad0, outPre, partial, partialSq);
    k_stats<<<CC, 256, 0, stream>>>(partial, partialSq, g0, b0, st0);
    k_gat<1><<<BB, TPB, 0, stream>>>(nullptr, nullptr, nullptr, outPre, st0,
                                     W1, as1, ad1, outPre, partial, partialSq);
    k_stats<<<CC, 256, 0, stream>>>(partial, partialSq, g1, b1, st1);
    k_final<<<BB, 256, 0, stream>>>(outPre, st1, outW, outb, out);
}

// Round 3
// 154.935 us; speedup vs baseline: 2.3685x; 1.2960x over previous
//
#include <hip/hip_runtime.h>
#include <cstdint>

// ChessGNN forward, MI355X.
// R2: f16 LDS tiles (x, W^T, h, P) + fdot2, register softmax, LDS ~51KB
//     -> 3 blocks/CU. f32 accumulation everywhere.

#define BB   2048
#define NN   90
#define CC   64
#define NH   4
#define HD   16
#define TPB  512
#define DOUT 128
#define SXP  72      // sx/sh row pitch in f16 (144B, 16B-aligned)
#define SWP  72      // sWt row pitch in f16
#define PPITCH 24    // sPh row pitch in f16 (48B, 16B-aligned)
#define MAXNBR 18

typedef _Float16 f16;
typedef _Float16 f16x2 __attribute__((ext_vector_type(2)));
typedef _Float16 f16x4 __attribute__((ext_vector_type(4)));
typedef _Float16 f16x8 __attribute__((ext_vector_type(8)));
union U16x8 { f16x8 v; f16x2 p[4]; f16 e[8]; };

__device__ __forceinline__ float dot2f(f16x2 a, f16x2 b, float c) {
#if __has_builtin(__builtin_amdgcn_fdot2)
    return __builtin_amdgcn_fdot2(a, b, c, false);
#else
    return fmaf((float)a.x, (float)b.x, fmaf((float)a.y, (float)b.y, c));
#endif
}

// union region (bytes):
//   phase 1-3: sWt f16[64][72]       [0, 9216)
//              sInW f32[16][64]      [9216, 13312)
//              sInb f32[64]          [13312, 13568)
//              sXr f32[90][17]       [13568, 19688)
//   phase 5-6: sPh f16[4][90][24]    [0, 17280)
//   phase 7:   sRa f32[2048] [0,8192), sRb f32[2048] [8192,16384)
#define UNI_BYTES 19712

template <int LAYER>
__global__ __launch_bounds__(TPB, 6) void k_gat(
    const float* __restrict__ bp,
    const float* __restrict__ inW,
    const float* __restrict__ inb,
    const float* __restrict__ prevPre,
    const float* __restrict__ stPrev,
    const float* __restrict__ Wl,
    const float* __restrict__ asrc,
    const float* __restrict__ adst,
    float* __restrict__ outPre,
    float* __restrict__ partial,
    float* __restrict__ partialSq)
{
    __shared__ __align__(16) unsigned char uni[UNI_BYTES];
    __shared__ __align__(16) f16 sx[NN][SXP];
    __shared__ __align__(16) f16 sh[NN][SXP];
    __shared__ __align__(16) f16 sAsH[NH * HD], sAdH[NH * HD];
    __shared__ float sSrc[NH][NN], sDst[NH][NN];
    __shared__ unsigned int sNbrP[NN][5];
    __shared__ unsigned char sCnt[NN];
    __shared__ float sST[2 * CC];

    f16*   sWt  = (f16*)uni;
    float* sInW = (float*)(uni + 9216);
    float* sInb = (float*)(uni + 13312);
    float* sXr  = (float*)(uni + 13568);
    f16*   sPh  = (f16*)uni;
    float* sRa  = (float*)uni;
    float* sRb  = (float*)(uni + 8192);

    const int b = blockIdx.x, t = threadIdx.x;
    const int cq = t & 15, ng = t >> 4;
    const int c4 = cq << 2;
    const int jcnt = (ng < NN - 64) ? 3 : 2;

    // ---------------- phase 1: stage weights / inputs / neighbor lists
    for (int i = t; i < CC * CC; i += TPB) {
        int k = i >> 6, c = i & 63;
        sWt[c * SWP + k] = (f16)Wl[i];
    }
    if (t < NH * HD) { sAsH[t] = (f16)asrc[t]; sAdH[t] = (f16)adst[t]; }

    if (LAYER == 0) {
        for (int i = t; i < 16 * CC; i += TPB) sInW[i] = inW[i];
        if (t < CC) sInb[t] = inb[t];
        const float* bpb = bp + (size_t)b * (14 * NN);
        for (int i = t; i < 14 * NN; i += TPB) {
            int p = i / NN, n = i - p * NN;
            sXr[n * 17 + p] = bpb[i];
        }
        if (t < NN) {
            int y = t / 9, x = t - y * 9;
            sXr[t * 17 + 14] = (float)x / 9.0f;
            sXr[t * 17 + 15] = (float)y / 10.0f;
        }
    } else {
        if (t < 2 * CC) sST[t] = stPrev[t];
    }

    if (t < NN) {
        int y = t / 9, x = t - y * 9;
        unsigned char nb[20];
        int cnt = 0;
        int x0 = x - 4; if (x0 < 0) x0 = 0;
        int x1 = x + 4; if (x1 > 8) x1 = 8;
        for (int xx = x0; xx <= x1; xx++) nb[cnt++] = (unsigned char)(y * 9 + xx);
        int y0 = y - 5; if (y0 < 0) y0 = 0;
        int y1 = y + 5; if (y1 > 9) y1 = 9;
        for (int yy = y0; yy <= y1; yy++)
            if (yy != y) nb[cnt++] = (unsigned char)(yy * 9 + x);
        for (int k = cnt; k < 20; k++) nb[k] = 0;
        #pragma unroll
        for (int q = 0; q < 5; q++)
            sNbrP[t][q] = (unsigned int)nb[4*q] | ((unsigned int)nb[4*q+1] << 8)
                        | ((unsigned int)nb[4*q+2] << 16) | ((unsigned int)nb[4*q+3] << 24);
        sCnt[t] = (unsigned char)cnt;
    }
    __syncthreads();

    // ---------------- phase 2: x -> sx (f16)
    if (LAYER == 0) {
        const int n0 = ng, n1 = ng + 32, n2 = (jcnt == 3) ? ng + 64 : ng;
        float acc[3][4] = {};
        #pragma unroll
        for (int k = 0; k < 16; k++) {
            float4 w = *(const float4*)&sInW[k * CC + c4];
            float x0 = sXr[n0 * 17 + k], x1 = sXr[n1 * 17 + k], x2 = sXr[n2 * 17 + k];
            acc[0][0] = fmaf(x0, w.x, acc[0][0]); acc[0][1] = fmaf(x0, w.y, acc[0][1]);
            acc[0][2] = fmaf(x0, w.z, acc[0][2]); acc[0][3] = fmaf(x0, w.w, acc[0][3]);
            acc[1][0] = fmaf(x1, w.x, acc[1][0]); acc[1][1] = fmaf(x1, w.y, acc[1][1]);
            acc[1][2] = fmaf(x1, w.z, acc[1][2]); acc[1][3] = fmaf(x1, w.w, acc[1][3]);
            acc[2][0] = fmaf(x2, w.x, acc[2][0]); acc[2][1] = fmaf(x2, w.y, acc[2][1]);
            acc[2][2] = fmaf(x2, w.z, acc[2][2]); acc[2][3] = fmaf(x2, w.w, acc[2][3]);
        }
        for (int j = 0; j < jcnt; j++) {
            int n = ng + 32 * j;
            f16x4 o;
            o.x = (f16)(acc[j][0] + sInb[c4 + 0]);
            o.y = (f16)(acc[j][1] + sInb[c4 + 1]);
            o.z = (f16)(acc[j][2] + sInb[c4 + 2]);
            o.w = (f16)(acc[j][3] + sInb[c4 + 3]);
            *(f16x4*)&sx[n][c4] = o;
        }
    } else {
        const float4* pv4 = (const float4*)(prevPre + (size_t)b * (NN * CC));
        for (int i4 = t; i4 < NN * CC / 4; i4 += TPB) {
            float4 v = pv4[i4];
            int n = i4 >> 4, c = (i4 & 15) << 2;
            float a0 = fmaf(v.x, sST[c + 0], sST[CC + c + 0]);
            float a1 = fmaf(v.y, sST[c + 1], sST[CC + c + 1]);
            float a2 = fmaf(v.z, sST[c + 2], sST[CC + c + 2]);
            float a3 = fmaf(v.w, sST[c + 3], sST[CC + c + 3]);
            f16x4 o;
            o.x = (f16)(a0 > 0.0f ? a0 : 0.0f);
            o.y = (f16)(a1 > 0.0f ? a1 : 0.0f);
            o.z = (f16)(a2 > 0.0f ? a2 : 0.0f);
            o.w = (f16)(a3 > 0.0f ? a3 : 0.0f);
            *(f16x4*)&sx[n][c] = o;
        }
    }
    __syncthreads();

    // ---------------- phase 3: h = x @ W -> sh (f16, fdot2, 8k per b128)
    {
        const int n0 = ng, n1 = ng + 32, n2 = (jcnt == 3) ? ng + 64 : ng;
        float acc[3][4] = {};
        #pragma unroll 2
        for (int k8 = 0; k8 < CC; k8 += 8) {
            U16x8 xa, xb, xc, w0, w1, w2, w3;
            xa.v = *(const f16x8*)&sx[n0][k8];
            xb.v = *(const f16x8*)&sx[n1][k8];
            xc.v = *(const f16x8*)&sx[n2][k8];
            w0.v = *(const f16x8*)&sWt[(c4 + 0) * SWP + k8];
            w1.v = *(const f16x8*)&sWt[(c4 + 1) * SWP + k8];
            w2.v = *(const f16x8*)&sWt[(c4 + 2) * SWP + k8];
            w3.v = *(const f16x8*)&sWt[(c4 + 3) * SWP + k8];
            #pragma unroll
            for (int i = 0; i < 4; i++) {
                acc[0][0] = dot2f(xa.p[i], w0.p[i], acc[0][0]);
                acc[0][1] = dot2f(xa.p[i], w1.p[i], acc[0][1]);
                acc[0][2] = dot2f(xa.p[i], w2.p[i], acc[0][2]);
                acc[0][3] = dot2f(xa.p[i], w3.p[i], acc[0][3]);
                acc[1][0] = dot2f(xb.p[i], w0.p[i], acc[1][0]);
                acc[1][1] = dot2f(xb.p[i], w1.p[i], acc[1][1]);
                acc[1][2] = dot2f(xb.p[i], w2.p[i], acc[1][2]);
                acc[1][3] = dot2f(xb.p[i], w3.p[i], acc[1][3]);
                acc[2][0] = dot2f(xc.p[i], w0.p[i], acc[2][0]);
                acc[2][1] = dot2f(xc.p[i], w1.p[i], acc[2][1]);
                acc[2][2] = dot2f(xc.p[i], w2.p[i], acc[2][2]);
                acc[2][3] = dot2f(xc.p[i], w3.p[i], acc[2][3]);
            }
        }
        for (int j = 0; j < jcnt; j++) {
            int n = ng + 32 * j;
            f16x4 o;
            o.x = (f16)acc[j][0]; o.y = (f16)acc[j][1];
            o.z = (f16)acc[j][2]; o.w = (f16)acc[j][3];
            *(f16x4*)&sh[n][c4] = o;
        }
    }
    __syncthreads();

    // ---------------- phase 4: attention scores per (head, node)
    if (t < NH * NN) {
        int hh = t / NN, n = t - hh * NN;
        U16x8 h0, h1, a0, a1, d0, d1;
        h0.v = *(const f16x8*)&sh[n][hh * HD];
        h1.v = *(const f16x8*)&sh[n][hh * HD + 8];
        a0.v = *(const f16x8*)&sAsH[hh * HD];
        a1.v = *(const f16x8*)&sAsH[hh * HD + 8];
        d0.v = *(const f16x8*)&sAdH[hh * HD];
        d1.v = *(const f16x8*)&sAdH[hh * HD + 8];
        float a = 0.0f, d = 0.0f;
        #pragma unroll
        for (int i = 0; i < 4; i++) {
            a = dot2f(h0.p[i], a0.p[i], a);
            a = dot2f(h1.p[i], a1.p[i], a);
            d = dot2f(h0.p[i], d0.p[i], d);
            d = dot2f(h1.p[i], d1.p[i], d);
        }
        sSrc[hh][n] = a; sDst[hh][n] = d;
    }
    __syncthreads();

    // ---------------- phase 5: softmax in registers -> sPh (f16, unnormalized)
    // inv sum stored into own sSrc slot (dead after read here).
    if (t < NH * NN) {
        int hh = t / NN, n = t - hh * NN;
        float si = sSrc[hh][n];
        int cnt = sCnt[n];
        unsigned int nb[5];
        #pragma unroll
        for (int q = 0; q < 5; q++) nb[q] = sNbrP[n][q];
        float ev[MAXNBR];
        float m = -1e30f;
        #pragma unroll
        for (int k = 0; k < MAXNBR; k++) {
            float e = -1e30f;
            if (k < cnt) {
                int j = (nb[k >> 2] >> (8 * (k & 3))) & 255;
                e = si + sDst[hh][j];
                e = e > 0.0f ? e : 0.2f * e;
                m = fmaxf(m, e);
            }
            ev[k] = e;
        }
        float s = 0.0f;
        f16* pr = &sPh[(hh * NN + n) * PPITCH];
        #pragma unroll
        for (int k = 0; k < MAXNBR; k++) {
            float p = __expf(ev[k] - m);
            if (k < cnt) { s += p; pr[k] = (f16)p; }
        }
        sSrc[hh][n] = 1.0f / s;
    }
    __syncthreads();

    // ---------------- phase 6: out = attn @ h over neighbors
    const int hh2 = cq >> 2;
    float lsum[4] = {}, lsq[4] = {};
    float* op = outPre + (size_t)b * (NN * CC);
    for (int j = 0; j < jcnt; j++) {
        int n = ng + 32 * j;
        int cnt = sCnt[n];
        float inv = sSrc[hh2][n];
        unsigned int nb[5];
        #pragma unroll
        for (int q = 0; q < 5; q++) nb[q] = sNbrP[n][q];
        const f16* pr = &sPh[(hh2 * NN + n) * PPITCH];
        U16x8 pA, pB;
        pA.v = *(const f16x8*)pr;
        pB.v = *(const f16x8*)(pr + 8);
        f16x2 pC = *(const f16x2*)(pr + 16);
        float a0 = 0.0f, a1 = 0.0f, a2 = 0.0f, a3 = 0.0f;
        #pragma unroll
        for (int k = 0; k < MAXNBR; k++) {
            if (k < cnt) {
                int jn = (nb[k >> 2] >> (8 * (k & 3))) & 255;
                float p = (k < 8) ? (float)pA.e[k]
                        : (k < 16) ? (float)pB.e[k - 8]
                        : (k == 16) ? (float)pC.x : (float)pC.y;
                f16x4 h4 = *(const f16x4*)&sh[jn][c4];
                a0 = fmaf(p, (float)h4.x, a0);
                a1 = fmaf(p, (float)h4.y, a1);
                a2 = fmaf(p, (float)h4.z, a2);
                a3 = fmaf(p, (float)h4.w, a3);
            }
        }
        a0 *= inv; a1 *= inv; a2 *= inv; a3 *= inv;
        float4 o; o.x = a0; o.y = a1; o.z = a2; o.w = a3;
        *(float4*)&op[n * CC + c4] = o;
        lsum[0] += a0; lsum[1] += a1; lsum[2] += a2; lsum[3] += a3;
        lsq[0] = fmaf(a0, a0, lsq[0]); lsq[1] = fmaf(a1, a1, lsq[1]);
        lsq[2] = fmaf(a2, a2, lsq[2]); lsq[3] = fmaf(a3, a3, lsq[3]);
    }
    __syncthreads();   // sPh dead beyond here

    // ---------------- phase 7: BN partial sums
    #pragma unroll
    for (int q = 0; q < 4; q++) {
        sRa[ng * CC + c4 + q] = lsum[q];
        sRb[ng * CC + c4 + q] = lsq[q];
    }
    __syncthreads();
    if (t < CC) {
        float s = 0.0f, q2 = 0.0f;
        #pragma unroll
        for (int g = 0; g < 32; g++) {
            s  += sRa[g * CC + t];
            q2 += sRb[g * CC + t];
        }
        partial[(size_t)b * CC + t] = s;
        partialSq[(size_t)b * CC + t] = q2;
    }
}

// ------------------------------------------------------------- BN statistics
__global__ __launch_bounds__(256) void k_stats(
    const float* __restrict__ partial, const float* __restrict__ partialSq,
    const float* __restrict__ gamma, const float* __restrict__ beta,
    float* __restrict__ st)
{
    const int c = blockIdx.x, t = threadIdx.x;
    float s = 0.0f, q = 0.0f;
    for (int b = t; b < BB; b += 256) {
        s += partial[(size_t)b * CC + c];
        q += partialSq[(size_t)b * CC + c];
    }
    __shared__ float rs[256], rq[256];
    rs[t] = s; rq[t] = q;
    __syncthreads();
    for (int o = 128; o > 0; o >>= 1) {
        if (t < o) { rs[t] += rs[t + o]; rq[t] += rq[t + o]; }
        __syncthreads();
    }
    if (t == 0) {
        const float cntInv = 1.0f / (float)(BB * NN);
        float mean = rs[0] * cntInv;
        float var  = rq[0] * cntInv - mean * mean;
        float sc = gamma[c] * rsqrtf(var + 1e-5f);
        st[c] = sc;
        st[CC + c] = beta[c] - mean * sc;
    }
}

// ------------------------------------------------------------------- final
__global__ __launch_bounds__(256) void k_final(
    const float* __restrict__ pre, const float* __restrict__ st,
    const float* __restrict__ outW, const float* __restrict__ outb,
    float* __restrict__ out)
{
    __shared__ float sM[CC];
    __shared__ float sPart[4][CC];
    const int b = blockIdx.x, t = threadIdx.x;
    const int c = t & 63, p = t >> 6;
    const float* pv = pre + (size_t)b * (NN * CC);
    float s = st[c], sft = st[CC + c];
    float a = 0.0f;
    int nBeg = p * 23, nEnd = nBeg + 23 < NN ? nBeg + 23 : NN;
    for (int n = nBeg; n < nEnd; n++) {
        float v = fmaf(pv[n * CC + c], s, sft);
        a += (v > 0.0f ? v : 0.0f);
    }
    sPart[p][c] = a;
    __syncthreads();
    if (t < CC)
        sM[t] = (sPart[0][t] + sPart[1][t] + sPart[2][t] + sPart[3][t]) * (1.0f / (float)NN);
    __syncthreads();
    if (t < DOUT) {
        float acc = outb[t];
        #pragma unroll
        for (int cc2 = 0; cc2 < CC; cc2++) acc = fmaf(sM[cc2], outW[cc2 * DOUT + t], acc);
        out[(size_t)b * DOUT + t] = acc;
    }
}

// ------------------------------------------------------------------ launch
extern "C" void kernel_launch(void* const* d_in, const int* in_sizes, int n_in,
                              void* d_out, int out_size, void* d_ws, size_t ws_size,
                              hipStream_t stream) {
    (void)in_sizes; (void)n_in; (void)out_size; (void)ws_size;

    const float* bp   = (const float*)d_in[0];
    const float* inW  = (const float*)d_in[1];
    const float* inb  = (const float*)d_in[2];
    const float* W0   = (const float*)d_in[3];
    const float* as0  = (const float*)d_in[4];
    const float* ad0  = (const float*)d_in[5];
    const float* g0   = (const float*)d_in[6];
    const float* b0   = (const float*)d_in[7];
    const float* W1   = (const float*)d_in[8];
    const float* as1  = (const float*)d_in[9];
    const float* ad1  = (const float*)d_in[10];
    const float* g1   = (const float*)d_in[11];
    const float* b1   = (const float*)d_in[12];
    const float* outW = (const float*)d_in[13];
    const float* outb = (const float*)d_in[14];
    float* out = (float*)d_out;

    float* ws = (float*)d_ws;
    float* outPre    = ws;
    float* partial   = outPre + (size_t)BB * NN * CC;
    float* partialSq = partial + (size_t)BB * CC;
    float* st0       = partialSq + (size_t)BB * CC;
    float* st1       = st0 + 2 * CC;

    k_gat<0><<<BB, TPB, 0, stream>>>(bp, inW, inb, nullptr, nullptr,
                                     W0, as0, ad0, outPre, partial, partialSq);
    k_stats<<<CC, 256, 0, stream>>>(partial, partialSq, g0, b0, st0);
    k_gat<1><<<BB, TPB, 0, stream>>>(nullptr, nullptr, nullptr, outPre, st0,
                                     W1, as1, ad1, outPre, partial, partialSq);
    k_stats<<<CC, 256, 0, stream>>>(partial, partialSq, g1, b1, st1);
    k_final<<<BB, 256, 0, stream>>>(outPre, st1, outW, outb, out);
}

// Round 4
// 145.621 us; speedup vs baseline: 2.5200x; 1.0640x over previous
//
#include <hip/hip_runtime.h>
#include <cstdint>

// ChessGNN forward, MI355X.
// R3: phase-3 GEMM (h = x@W, 96x64x64) moved to MFMA f32_16x16x32_f16.
//     f16 LDS tiles, register softmax, LDS ~53KB -> 3 blocks/CU.

#define BB   2048
#define NN   90
#define NP   96      // padded node count for MFMA M-tiles
#define CC   64
#define NH   4
#define HD   16
#define TPB  512
#define DOUT 128
#define SXP  72      // sx/sh row pitch in f16 (144B, 16B-aligned)
#define SWP  72      // sWt row pitch in f16
#define PPITCH 24    // sPh row pitch in f16 (48B, 16B-aligned)
#define MAXNBR 18

typedef _Float16 f16;
typedef _Float16 f16x2 __attribute__((ext_vector_type(2)));
typedef _Float16 f16x4 __attribute__((ext_vector_type(4)));
typedef _Float16 f16x8 __attribute__((ext_vector_type(8)));
typedef float f32x4 __attribute__((ext_vector_type(4)));
union U16x8 { f16x8 v; f16x2 p[4]; f16 e[8]; };

__device__ __forceinline__ float dot2f(f16x2 a, f16x2 b, float c) {
#if __has_builtin(__builtin_amdgcn_fdot2)
    return __builtin_amdgcn_fdot2(a, b, c, false);
#else
    return fmaf((float)a.x, (float)b.x, fmaf((float)a.y, (float)b.y, c));
#endif
}

// union region (bytes):
//   phase 1-3: sWt f16[64][72]       [0, 9216)
//              sInW f32[16][64]      [9216, 13312)
//              sInb f32[64]          [13312, 13568)
//              sXr f32[90][17]       [13568, 19688)
//   phase 5-6: sPh f16[4][90][24]    [0, 17280)
//   phase 7:   sRa f32[2048] [0,8192), sRb f32[2048] [8192,16384)
#define UNI_BYTES 19712

template <int LAYER>
__global__ __launch_bounds__(TPB, 6) void k_gat(
    const float* __restrict__ bp,
    const float* __restrict__ inW,
    const float* __restrict__ inb,
    const float* __restrict__ prevPre,
    const float* __restrict__ stPrev,
    const float* __restrict__ Wl,
    const float* __restrict__ asrc,
    const float* __restrict__ adst,
    float* __restrict__ outPre,
    float* __restrict__ partial,
    float* __restrict__ partialSq)
{
    __shared__ __align__(16) unsigned char uni[UNI_BYTES];
    __shared__ __align__(16) f16 sx[NP][SXP];
    __shared__ __align__(16) f16 sh[NP][SXP];
    __shared__ __align__(16) f16 sAsH[NH * HD], sAdH[NH * HD];
    __shared__ float sSrc[NH][NN], sDst[NH][NN];
    __shared__ unsigned int sNbrP[NN][5];
    __shared__ unsigned char sCnt[NN];
    __shared__ float sST[2 * CC];

    f16*   sWt  = (f16*)uni;
    float* sInW = (float*)(uni + 9216);
    float* sInb = (float*)(uni + 13312);
    float* sXr  = (float*)(uni + 13568);
    f16*   sPh  = (f16*)uni;
    float* sRa  = (float*)uni;
    float* sRb  = (float*)(uni + 8192);

    const int b = blockIdx.x, t = threadIdx.x;
    const int cq = t & 15, ng = t >> 4;
    const int c4 = cq << 2;
    const int jcnt = (ng < NN - 64) ? 3 : 2;

    // ---------------- phase 1: stage weights / inputs / neighbor lists
    for (int i = t; i < CC * CC; i += TPB) {
        int k = i >> 6, c = i & 63;
        sWt[c * SWP + k] = (f16)Wl[i];
    }
    if (t < NH * HD) { sAsH[t] = (f16)asrc[t]; sAdH[t] = (f16)adst[t]; }

    // zero pad rows 90..95 of sx (MFMA M-padding)
    if (t < (NP - NN) * (SXP / 4)) {
        int r = t / (SXP / 4), q = t % (SXP / 4);
        f16x4 z = {(f16)0, (f16)0, (f16)0, (f16)0};
        *(f16x4*)&sx[NN + r][q * 4] = z;
    }

    if (LAYER == 0) {
        for (int i = t; i < 16 * CC; i += TPB) sInW[i] = inW[i];
        if (t < CC) sInb[t] = inb[t];
        const float* bpb = bp + (size_t)b * (14 * NN);
        for (int i = t; i < 14 * NN; i += TPB) {
            int p = i / NN, n = i - p * NN;
            sXr[n * 17 + p] = bpb[i];
        }
        if (t < NN) {
            int y = t / 9, x = t - y * 9;
            sXr[t * 17 + 14] = (float)x / 9.0f;
            sXr[t * 17 + 15] = (float)y / 10.0f;
        }
    } else {
        if (t < 2 * CC) sST[t] = stPrev[t];
    }

    if (t < NN) {
        int y = t / 9, x = t - y * 9;
        unsigned char nb[20];
        int cnt = 0;
        int x0 = x - 4; if (x0 < 0) x0 = 0;
        int x1 = x + 4; if (x1 > 8) x1 = 8;
        for (int xx = x0; xx <= x1; xx++) nb[cnt++] = (unsigned char)(y * 9 + xx);
        int y0 = y - 5; if (y0 < 0) y0 = 0;
        int y1 = y + 5; if (y1 > 9) y1 = 9;
        for (int yy = y0; yy <= y1; yy++)
            if (yy != y) nb[cnt++] = (unsigned char)(yy * 9 + x);
        for (int k = cnt; k < 20; k++) nb[k] = 0;
        #pragma unroll
        for (int q = 0; q < 5; q++)
            sNbrP[t][q] = (unsigned int)nb[4*q] | ((unsigned int)nb[4*q+1] << 8)
                        | ((unsigned int)nb[4*q+2] << 16) | ((unsigned int)nb[4*q+3] << 24);
        sCnt[t] = (unsigned char)cnt;
    }
    __syncthreads();

    // ---------------- phase 2: x -> sx (f16)
    if (LAYER == 0) {
        const int n0 = ng, n1 = ng + 32, n2 = (jcnt == 3) ? ng + 64 : ng;
        float acc[3][4] = {};
        #pragma unroll
        for (int k = 0; k < 16; k++) {
            float4 w = *(const float4*)&sInW[k * CC + c4];
            float x0 = sXr[n0 * 17 + k], x1 = sXr[n1 * 17 + k], x2 = sXr[n2 * 17 + k];
            acc[0][0] = fmaf(x0, w.x, acc[0][0]); acc[0][1] = fmaf(x0, w.y, acc[0][1]);
            acc[0][2] = fmaf(x0, w.z, acc[0][2]); acc[0][3] = fmaf(x0, w.w, acc[0][3]);
            acc[1][0] = fmaf(x1, w.x, acc[1][0]); acc[1][1] = fmaf(x1, w.y, acc[1][1]);
            acc[1][2] = fmaf(x1, w.z, acc[1][2]); acc[1][3] = fmaf(x1, w.w, acc[1][3]);
            acc[2][0] = fmaf(x2, w.x, acc[2][0]); acc[2][1] = fmaf(x2, w.y, acc[2][1]);
            acc[2][2] = fmaf(x2, w.z, acc[2][2]); acc[2][3] = fmaf(x2, w.w, acc[2][3]);
        }
        for (int j = 0; j < jcnt; j++) {
            int n = ng + 32 * j;
            f16x4 o;
            o.x = (f16)(acc[j][0] + sInb[c4 + 0]);
            o.y = (f16)(acc[j][1] + sInb[c4 + 1]);
            o.z = (f16)(acc[j][2] + sInb[c4 + 2]);
            o.w = (f16)(acc[j][3] + sInb[c4 + 3]);
            *(f16x4*)&sx[n][c4] = o;
        }
    } else {
        const float4* pv4 = (const float4*)(prevPre + (size_t)b * (NN * CC));
        for (int i4 = t; i4 < NN * CC / 4; i4 += TPB) {
            float4 v = pv4[i4];
            int n = i4 >> 4, c = (i4 & 15) << 2;
            float a0 = fmaf(v.x, sST[c + 0], sST[CC + c + 0]);
            float a1 = fmaf(v.y, sST[c + 1], sST[CC + c + 1]);
            float a2 = fmaf(v.z, sST[c + 2], sST[CC + c + 2]);
            float a3 = fmaf(v.w, sST[c + 3], sST[CC + c + 3]);
            f16x4 o;
            o.x = (f16)(a0 > 0.0f ? a0 : 0.0f);
            o.y = (f16)(a1 > 0.0f ? a1 : 0.0f);
            o.z = (f16)(a2 > 0.0f ? a2 : 0.0f);
            o.w = (f16)(a3 > 0.0f ? a3 : 0.0f);
            *(f16x4*)&sx[n][c] = o;
        }
    }
    __syncthreads();

    // ---------------- phase 3: h = x @ W via MFMA f32_16x16x32_f16
    // Per wave: N-tile nt = w&3 (16 channels), M-tiles m0, m0+2, m0+4 (m0 = w>>2).
    // A: row = lane&15 (+16*mt), k = (lane>>4)*8 + j   (row-major sx)
    // B: col = lane&15 (+16*nt), k = (lane>>4)*8 + j   (sWt = W^T rows)
    // C: col = lane&15, row = (lane>>4)*4 + r
    {
        const int w = t >> 6, lane = t & 63;
        const int lr = lane & 15, lg = lane >> 4;
        const int nt = w & 3, m0 = w >> 2;
        const f16x8 b0 = *(const f16x8*)&sWt[(nt * 16 + lr) * SWP + lg * 8];
        const f16x8 b1 = *(const f16x8*)&sWt[(nt * 16 + lr) * SWP + 32 + lg * 8];
        #pragma unroll
        for (int mi = 0; mi < 3; mi++) {
            const int mt = m0 + 2 * mi;
            const f16x8 a0 = *(const f16x8*)&sx[mt * 16 + lr][lg * 8];
            const f16x8 a1 = *(const f16x8*)&sx[mt * 16 + lr][32 + lg * 8];
            f32x4 acc = {0.0f, 0.0f, 0.0f, 0.0f};
            acc = __builtin_amdgcn_mfma_f32_16x16x32_f16(a0, b0, acc, 0, 0, 0);
            acc = __builtin_amdgcn_mfma_f32_16x16x32_f16(a1, b1, acc, 0, 0, 0);
            const int row = mt * 16 + lg * 4, col = nt * 16 + lr;
            sh[row + 0][col] = (f16)acc[0];
            sh[row + 1][col] = (f16)acc[1];
            sh[row + 2][col] = (f16)acc[2];
            sh[row + 3][col] = (f16)acc[3];
        }
    }
    __syncthreads();

    // ---------------- phase 4: attention scores per (head, node)
    if (t < NH * NN) {
        int hh = t / NN, n = t - hh * NN;
        U16x8 h0, h1, a0, a1, d0, d1;
        h0.v = *(const f16x8*)&sh[n][hh * HD];
        h1.v = *(const f16x8*)&sh[n][hh * HD + 8];
        a0.v = *(const f16x8*)&sAsH[hh * HD];
        a1.v = *(const f16x8*)&sAsH[hh * HD + 8];
        d0.v = *(const f16x8*)&sAdH[hh * HD];
        d1.v = *(const f16x8*)&sAdH[hh * HD + 8];
        float a = 0.0f, d = 0.0f;
        #pragma unroll
        for (int i = 0; i < 4; i++) {
            a = dot2f(h0.p[i], a0.p[i], a);
            a = dot2f(h1.p[i], a1.p[i], a);
            d = dot2f(h0.p[i], d0.p[i], d);
            d = dot2f(h1.p[i], d1.p[i], d);
        }
        sSrc[hh][n] = a; sDst[hh][n] = d;
    }
    __syncthreads();

    // ---------------- phase 5: softmax in registers -> sPh (f16, unnormalized)
    if (t < NH * NN) {
        int hh = t / NN, n = t - hh * NN;
        float si = sSrc[hh][n];
        int cnt = sCnt[n];
        unsigned int nb[5];
        #pragma unroll
        for (int q = 0; q < 5; q++) nb[q] = sNbrP[n][q];
        float ev[MAXNBR];
        float m = -1e30f;
        #pragma unroll
        for (int k = 0; k < MAXNBR; k++) {
            float e = -1e30f;
            if (k < cnt) {
                int j = (nb[k >> 2] >> (8 * (k & 3))) & 255;
                e = si + sDst[hh][j];
                e = e > 0.0f ? e : 0.2f * e;
                m = fmaxf(m, e);
            }
            ev[k] = e;
        }
        float s = 0.0f;
        f16* pr = &sPh[(hh * NN + n) * PPITCH];
        #pragma unroll
        for (int k = 0; k < MAXNBR; k++) {
            float p = __expf(ev[k] - m);
            if (k < cnt) { s += p; pr[k] = (f16)p; }
        }
        sSrc[hh][n] = 1.0f / s;
    }
    __syncthreads();

    // ---------------- phase 6: out = attn @ h over neighbors
    const int hh2 = cq >> 2;
    float lsum[4] = {}, lsq[4] = {};
    float* op = outPre + (size_t)b * (NN * CC);
    for (int j = 0; j < jcnt; j++) {
        int n = ng + 32 * j;
        int cnt = sCnt[n];
        float inv = sSrc[hh2][n];
        unsigned int nb[5];
        #pragma unroll
        for (int q = 0; q < 5; q++) nb[q] = sNbrP[n][q];
        const f16* pr = &sPh[(hh2 * NN + n) * PPITCH];
        U16x8 pA, pB;
        pA.v = *(const f16x8*)pr;
        pB.v = *(const f16x8*)(pr + 8);
        f16x2 pC = *(const f16x2*)(pr + 16);
        float a0 = 0.0f, a1 = 0.0f, a2 = 0.0f, a3 = 0.0f;
        #pragma unroll
        for (int k = 0; k < MAXNBR; k++) {
            if (k < cnt) {
                int jn = (nb[k >> 2] >> (8 * (k & 3))) & 255;
                float p = (k < 8) ? (float)pA.e[k]
                        : (k < 16) ? (float)pB.e[k - 8]
                        : (k == 16) ? (float)pC.x : (float)pC.y;
                f16x4 h4 = *(const f16x4*)&sh[jn][c4];
                a0 = fmaf(p, (float)h4.x, a0);
                a1 = fmaf(p, (float)h4.y, a1);
                a2 = fmaf(p, (float)h4.z, a2);
                a3 = fmaf(p, (float)h4.w, a3);
            }
        }
        a0 *= inv; a1 *= inv; a2 *= inv; a3 *= inv;
        float4 o; o.x = a0; o.y = a1; o.z = a2; o.w = a3;
        *(float4*)&op[n * CC + c4] = o;
        lsum[0] += a0; lsum[1] += a1; lsum[2] += a2; lsum[3] += a3;
        lsq[0] = fmaf(a0, a0, lsq[0]); lsq[1] = fmaf(a1, a1, lsq[1]);
        lsq[2] = fmaf(a2, a2, lsq[2]); lsq[3] = fmaf(a3, a3, lsq[3]);
    }
    __syncthreads();   // sPh dead beyond here

    // ---------------- phase 7: BN partial sums
    #pragma unroll
    for (int q = 0; q < 4; q++) {
        sRa[ng * CC + c4 + q] = lsum[q];
        sRb[ng * CC + c4 + q] = lsq[q];
    }
    __syncthreads();
    if (t < CC) {
        float s = 0.0f, q2 = 0.0f;
        #pragma unroll
        for (int g = 0; g < 32; g++) {
            s  += sRa[g * CC + t];
            q2 += sRb[g * CC + t];
        }
        partial[(size_t)b * CC + t] = s;
        partialSq[(size_t)b * CC + t] = q2;
    }
}

// ------------------------------------------------------------- BN statistics
__global__ __launch_bounds__(256) void k_stats(
    const float* __restrict__ partial, const float* __restrict__ partialSq,
    const float* __restrict__ gamma, const float* __restrict__ beta,
    float* __restrict__ st)
{
    const int c = blockIdx.x, t = threadIdx.x;
    float s = 0.0f, q = 0.0f;
    for (int b = t; b < BB; b += 256) {
        s += partial[(size_t)b * CC + c];
        q += partialSq[(size_t)b * CC + c];
    }
    __shared__ float rs[256], rq[256];
    rs[t] = s; rq[t] = q;
    __syncthreads();
    for (int o = 128; o > 0; o >>= 1) {
        if (t < o) { rs[t] += rs[t + o]; rq[t] += rq[t + o]; }
        __syncthreads();
    }
    if (t == 0) {
        const float cntInv = 1.0f / (float)(BB * NN);
        float mean = rs[0] * cntInv;
        float var  = rq[0] * cntInv - mean * mean;
        float sc = gamma[c] * rsqrtf(var + 1e-5f);
        st[c] = sc;
        st[CC + c] = beta[c] - mean * sc;
    }
}

// ------------------------------------------------------------------- final
__global__ __launch_bounds__(256) void k_final(
    const float* __restrict__ pre, const float* __restrict__ st,
    const float* __restrict__ outW, const float* __restrict__ outb,
    float* __restrict__ out)
{
    __shared__ float sM[CC];
    __shared__ float sPart[4][CC];
    const int b = blockIdx.x, t = threadIdx.x;
    const int c = t & 63, p = t >> 6;
    const float* pv = pre + (size_t)b * (NN * CC);
    float s = st[c], sft = st[CC + c];
    float a = 0.0f;
    int nBeg = p * 23, nEnd = nBeg + 23 < NN ? nBeg + 23 : NN;
    for (int n = nBeg; n < nEnd; n++) {
        float v = fmaf(pv[n * CC + c], s, sft);
        a += (v > 0.0f ? v : 0.0f);
    }
    sPart[p][c] = a;
    __syncthreads();
    if (t < CC)
        sM[t] = (sPart[0][t] + sPart[1][t] + sPart[2][t] + sPart[3][t]) * (1.0f / (float)NN);
    __syncthreads();
    if (t < DOUT) {
        float acc = outb[t];
        #pragma unroll
        for (int cc2 = 0; cc2 < CC; cc2++) acc = fmaf(sM[cc2], outW[cc2 * DOUT + t], acc);
        out[(size_t)b * DOUT + t] = acc;
    }
}

// ------------------------------------------------------------------ launch
extern "C" void kernel_launch(void* const* d_in, const int* in_sizes, int n_in,
                              void* d_out, int out_size, void* d_ws, size_t ws_size,
                              hipStream_t stream) {
    (void)in_sizes; (void)n_in; (void)out_size; (void)ws_size;

    const float* bp   = (const float*)d_in[0];
    const float* inW  = (const float*)d_in[1];
    const float* inb  = (const float*)d_in[2];
    const float* W0   = (const float*)d_in[3];
    const float* as0  = (const float*)d_in[4];
    const float* ad0  = (const float*)d_in[5];
    const float* g0   = (const float*)d_in[6];
    const float* b0   = (const float*)d_in[7];
    const float* W1   = (const float*)d_in[8];
    const float* as1  = (const float*)d_in[9];
    const float* ad1  = (const float*)d_in[10];
    const float* g1   = (const float*)d_in[11];
    const float* b1   = (const float*)d_in[12];
    const float* outW = (const float*)d_in[13];
    const float* outb = (const float*)d_in[14];
    float* out = (float*)d_out;

    float* ws = (float*)d_ws;
    float* outPre    = ws;
    float* partial   = outPre + (size_t)BB * NN * CC;
    float* partialSq = partial + (size_t)BB * CC;
    float* st0       = partialSq + (size_t)BB * CC;
    float* st1       = st0 + 2 * CC;

    k_gat<0><<<BB, TPB, 0, stream>>>(bp, inW, inb, nullptr, nullptr,
                                     W0, as0, ad0, outPre, partial, partialSq);
    k_stats<<<CC, 256, 0, stream>>>(partial, partialSq, g0, b0, st0);
    k_gat<1><<<BB, TPB, 0, stream>>>(nullptr, nullptr, nullptr, outPre, st0,
                                     W1, as1, ad1, outPre, partial, partialSq);
    k_stats<<<CC, 256, 0, stream>>>(partial, partialSq, g1, b1, st1);
    k_final<<<BB, 256, 0, stream>>>(outPre, st1, outW, outb, out);
}

// Round 5
// 109.005 us; speedup vs baseline: 3.3665x; 1.3359x over previous
//
#include <hip/hip_runtime.h>
#include <cstdint>

// ChessGNN forward, MI355X.
// R4: h kept in f32 (MFMA C written to shF overlaying sx+sh; frag-preload
//     barrier makes the overlay safe); fixed-19-slot positional softmax
//     (no neighbor tables, no index decode in aggregation).

#define BB   2048
#define NN   90
#define NP   96      // padded node count for MFMA M-tiles
#define CC   64
#define NH   4
#define HD   16
#define TPB  512
#define DOUT 128
#define SWP  72      // sWt row pitch in f16
#define SHP  72      // shF row pitch in f32 / sx row pitch in f16
#define PPITCH 24    // sPh row pitch in f16 (48B, 16B-aligned)
#define NSLOT 19     // 9 row slots + 10 col slots

typedef _Float16 f16;
typedef _Float16 f16x4 __attribute__((ext_vector_type(4)));
typedef _Float16 f16x8 __attribute__((ext_vector_type(8)));
typedef float f32x4 __attribute__((ext_vector_type(4)));
union U16x8 { f16x8 v; f16 e[8]; };
union U16x4 { f16x4 v; f16 e[4]; };

// uni region (bytes):
//   phase 1-3: sWt f16[64][72] [0,9216) | sInW f32[16*64] [9216,13312)
//              sInb f32[64] [13312,13568) | sXr f32[90*17] [13568,19688)
//   phase 5-6: sPh f16[4][90][24] [0,17280)
//   phase 7:   sRa f32[2048] [0,8192) | sRb f32[2048] [8192,16384)
#define UNI_BYTES 19712
// big region: sx f16[96][72] [0,13824)  -> overlaid by shF f32[96][72] [0,27648)
#define BIG_BYTES 27648

template <int LAYER>
__global__ __launch_bounds__(TPB, 6) void k_gat(
    const float* __restrict__ bp,
    const float* __restrict__ inW,
    const float* __restrict__ inb,
    const float* __restrict__ prevPre,
    const float* __restrict__ stPrev,
    const float* __restrict__ Wl,
    const float* __restrict__ asrc,
    const float* __restrict__ adst,
    float* __restrict__ outPre,
    float* __restrict__ partial,
    float* __restrict__ partialSq)
{
    __shared__ __align__(16) unsigned char uni[UNI_BYTES];
    __shared__ __align__(16) unsigned char big[BIG_BYTES];
    __shared__ float sAs[NH * HD], sAd[NH * HD];
    __shared__ float sSrc[NH][NN], sDst[NH][NN];
    __shared__ float sST[2 * CC];

    f16*   sWt  = (f16*)uni;
    float* sInW = (float*)(uni + 9216);
    float* sInb = (float*)(uni + 13312);
    float* sXr  = (float*)(uni + 13568);
    f16*   sPh  = (f16*)uni;
    float* sRa  = (float*)uni;
    float* sRb  = (float*)(uni + 8192);
    f16*   sx   = (f16*)big;        // [96][72] f16 (phases 1-3)
    float* shF  = (float*)big;      // [96][72] f32 (phases 3-6, overlays sx)

    const int b = blockIdx.x, t = threadIdx.x;
    const int cq = t & 15, ng = t >> 4;
    const int c4 = cq << 2;
    const int jcnt = (ng < NN - 64) ? 3 : 2;

    // ---------------- phase 1: stage weights / inputs
    for (int i = t; i < CC * CC; i += TPB) {
        int k = i >> 6, c = i & 63;
        sWt[c * SWP + k] = (f16)Wl[i];
    }
    if (t < NH * HD) { sAs[t] = asrc[t]; sAd[t] = adst[t]; }

    // zero pad rows 90..95 of sx (MFMA M-padding)
    if (t < (NP - NN) * (SHP / 4)) {
        int r = t / (SHP / 4), q = t % (SHP / 4);
        f16x4 z = {(f16)0, (f16)0, (f16)0, (f16)0};
        *(f16x4*)&sx[(NN + r) * SHP + q * 4] = z;
    }

    if (LAYER == 0) {
        for (int i = t; i < 16 * CC; i += TPB) sInW[i] = inW[i];
        if (t < CC) sInb[t] = inb[t];
        const float* bpb = bp + (size_t)b * (14 * NN);
        for (int i = t; i < 14 * NN; i += TPB) {
            int p = i / NN, n = i - p * NN;
            sXr[n * 17 + p] = bpb[i];
        }
        if (t < NN) {
            int y = t / 9, x = t - y * 9;
            sXr[t * 17 + 14] = (float)x / 9.0f;
            sXr[t * 17 + 15] = (float)y / 10.0f;
        }
    } else {
        if (t < 2 * CC) sST[t] = stPrev[t];
    }
    __syncthreads();

    // ---------------- phase 2: x -> sx (f16)
    if (LAYER == 0) {
        const int n0 = ng, n1 = ng + 32, n2 = (jcnt == 3) ? ng + 64 : ng;
        float acc[3][4] = {};
        #pragma unroll
        for (int k = 0; k < 16; k++) {
            float4 w = *(const float4*)&sInW[k * CC + c4];
            float x0 = sXr[n0 * 17 + k], x1 = sXr[n1 * 17 + k], x2 = sXr[n2 * 17 + k];
            acc[0][0] = fmaf(x0, w.x, acc[0][0]); acc[0][1] = fmaf(x0, w.y, acc[0][1]);
            acc[0][2] = fmaf(x0, w.z, acc[0][2]); acc[0][3] = fmaf(x0, w.w, acc[0][3]);
            acc[1][0] = fmaf(x1, w.x, acc[1][0]); acc[1][1] = fmaf(x1, w.y, acc[1][1]);
            acc[1][2] = fmaf(x1, w.z, acc[1][2]); acc[1][3] = fmaf(x1, w.w, acc[1][3]);
            acc[2][0] = fmaf(x2, w.x, acc[2][0]); acc[2][1] = fmaf(x2, w.y, acc[2][1]);
            acc[2][2] = fmaf(x2, w.z, acc[2][2]); acc[2][3] = fmaf(x2, w.w, acc[2][3]);
        }
        for (int j = 0; j < jcnt; j++) {
            int n = ng + 32 * j;
            f16x4 o;
            o.x = (f16)(acc[j][0] + sInb[c4 + 0]);
            o.y = (f16)(acc[j][1] + sInb[c4 + 1]);
            o.z = (f16)(acc[j][2] + sInb[c4 + 2]);
            o.w = (f16)(acc[j][3] + sInb[c4 + 3]);
            *(f16x4*)&sx[n * SHP + c4] = o;
        }
    } else {
        const float4* pv4 = (const float4*)(prevPre + (size_t)b * (NN * CC));
        for (int i4 = t; i4 < NN * CC / 4; i4 += TPB) {
            float4 v = pv4[i4];
            int n = i4 >> 4, c = (i4 & 15) << 2;
            float a0 = fmaf(v.x, sST[c + 0], sST[CC + c + 0]);
            float a1 = fmaf(v.y, sST[c + 1], sST[CC + c + 1]);
            float a2 = fmaf(v.z, sST[c + 2], sST[CC + c + 2]);
            float a3 = fmaf(v.w, sST[c + 3], sST[CC + c + 3]);
            f16x4 o;
            o.x = (f16)(a0 > 0.0f ? a0 : 0.0f);
            o.y = (f16)(a1 > 0.0f ? a1 : 0.0f);
            o.z = (f16)(a2 > 0.0f ? a2 : 0.0f);
            o.w = (f16)(a3 > 0.0f ? a3 : 0.0f);
            *(f16x4*)&sx[n * SHP + c] = o;
        }
    }
    __syncthreads();

    // ---------------- phase 3: h = x @ W via MFMA, C written as f32 to shF
    // (overlays sx: all frags preloaded to registers, then barrier, then MFMA)
    {
        const int w = t >> 6, lane = t & 63;
        const int lr = lane & 15, lg = lane >> 4;
        const int nt = w & 3, m0 = w >> 2;
        const f16x8 bf0 = *(const f16x8*)&sWt[(nt * 16 + lr) * SWP + lg * 8];
        const f16x8 bf1 = *(const f16x8*)&sWt[(nt * 16 + lr) * SWP + 32 + lg * 8];
        f16x8 af0[3], af1[3];
        #pragma unroll
        for (int mi = 0; mi < 3; mi++) {
            const int mt = m0 + 2 * mi;
            af0[mi] = *(const f16x8*)&sx[(mt * 16 + lr) * SHP + lg * 8];
            af1[mi] = *(const f16x8*)&sx[(mt * 16 + lr) * SHP + 32 + lg * 8];
        }
        __syncthreads();   // all sx reads done; shF writes may begin
        #pragma unroll
        for (int mi = 0; mi < 3; mi++) {
            const int mt = m0 + 2 * mi;
            f32x4 acc = {0.0f, 0.0f, 0.0f, 0.0f};
            acc = __builtin_amdgcn_mfma_f32_16x16x32_f16(af0[mi], bf0, acc, 0, 0, 0);
            acc = __builtin_amdgcn_mfma_f32_16x16x32_f16(af1[mi], bf1, acc, 0, 0, 0);
            const int row = mt * 16 + lg * 4, col = nt * 16 + lr;
            shF[(row + 0) * SHP + col] = acc[0];
            shF[(row + 1) * SHP + col] = acc[1];
            shF[(row + 2) * SHP + col] = acc[2];
            shF[(row + 3) * SHP + col] = acc[3];
        }
    }
    __syncthreads();

    // ---------------- phase 4: attention scores per (head, node), f32
    if (t < NH * NN) {
        int hh = t / NN, n = t - hh * NN;
        const float4* hv = (const float4*)&shF[n * SHP + hh * HD];
        float a = 0.0f, d = 0.0f;
        #pragma unroll
        for (int m = 0; m < 4; m++) {
            float4 h4 = hv[m];
            a = fmaf(h4.x, sAs[hh * HD + 4 * m + 0], a);
            a = fmaf(h4.y, sAs[hh * HD + 4 * m + 1], a);
            a = fmaf(h4.z, sAs[hh * HD + 4 * m + 2], a);
            a = fmaf(h4.w, sAs[hh * HD + 4 * m + 3], a);
            d = fmaf(h4.x, sAd[hh * HD + 4 * m + 0], d);
            d = fmaf(h4.y, sAd[hh * HD + 4 * m + 1], d);
            d = fmaf(h4.z, sAd[hh * HD + 4 * m + 2], d);
            d = fmaf(h4.w, sAd[hh * HD + 4 * m + 3], d);
        }
        sSrc[hh][n] = a; sDst[hh][n] = d;
    }
    __syncthreads();

    // ---------------- phase 5: positional-slot softmax -> sPh (f16, unnorm)
    // slot xx in [0,9): row-neighbor at column xx (0 if |xx-x|>4)
    // slot 9+yy in [9,19): col-neighbor at row yy (0 if yy==y or |yy-y|>5)
    if (t < NH * NN) {
        int hh = t / NN, n = t - hh * NN;
        int y = n / 9, x = n - y * 9;
        float si = sSrc[hh][n];
        float e[NSLOT];
        #pragma unroll
        for (int xx = 0; xx < 9; xx++) {
            int dx = xx > x ? xx - x : x - xx;
            float ee = si + sDst[hh][y * 9 + xx];
            ee = ee > 0.0f ? ee : 0.2f * ee;
            e[xx] = (dx <= 4) ? ee : -1e30f;
        }
        #pragma unroll
        for (int yy = 0; yy < 10; yy++) {
            int dy = yy > y ? yy - y : y - yy;
            float ee = si + sDst[hh][yy * 9 + x];
            ee = ee > 0.0f ? ee : 0.2f * ee;
            e[9 + yy] = (dy >= 1 && dy <= 5) ? ee : -1e30f;
        }
        float m = e[0];
        #pragma unroll
        for (int k = 1; k < NSLOT; k++) m = fmaxf(m, e[k]);
        float s = 0.0f;
        f16* pr = &sPh[(hh * NN + n) * PPITCH];
        #pragma unroll
        for (int k = 0; k < NSLOT; k++) {
            float p = __expf(e[k] - m);
            s += p;
            pr[k] = (f16)p;
        }
        sSrc[hh][n] = 1.0f / s;
    }
    __syncthreads();

    // ---------------- phase 6: out = attn @ h, fixed 19-slot loops, f32 h
    const int hh2 = cq >> 2;
    float lsum[4] = {}, lsq[4] = {};
    float* op = outPre + (size_t)b * (NN * CC);
    for (int j = 0; j < jcnt; j++) {
        int n = ng + 32 * j;
        int y = n / 9, x = n - y * 9;
        float inv = sSrc[hh2][n];
        const f16* pr = &sPh[(hh2 * NN + n) * PPITCH];
        U16x8 pA, pB; U16x4 pT;
        pA.v = *(const f16x8*)pr;
        pB.v = *(const f16x8*)(pr + 8);
        pT.v = *(const f16x4*)(pr + 16);
        float a0 = 0.0f, a1 = 0.0f, a2 = 0.0f, a3 = 0.0f;
        #pragma unroll
        for (int xx = 0; xx < 9; xx++) {
            float p = (xx < 8) ? (float)pA.e[xx] : (float)pB.e[0];
            float4 h4 = *(const float4*)&shF[(y * 9 + xx) * SHP + c4];
            a0 = fmaf(p, h4.x, a0); a1 = fmaf(p, h4.y, a1);
            a2 = fmaf(p, h4.z, a2); a3 = fmaf(p, h4.w, a3);
        }
        #pragma unroll
        for (int yy = 0; yy < 10; yy++) {
            int k = 9 + yy;
            float p = (k < 16) ? (float)pB.e[k - 8] : (float)pT.e[k - 16];
            float4 h4 = *(const float4*)&shF[(yy * 9 + x) * SHP + c4];
            a0 = fmaf(p, h4.x, a0); a1 = fmaf(p, h4.y, a1);
            a2 = fmaf(p, h4.z, a2); a3 = fmaf(p, h4.w, a3);
        }
        a0 *= inv; a1 *= inv; a2 *= inv; a3 *= inv;
        float4 o; o.x = a0; o.y = a1; o.z = a2; o.w = a3;
        *(float4*)&op[n * CC + c4] = o;
        lsum[0] += a0; lsum[1] += a1; lsum[2] += a2; lsum[3] += a3;
        lsq[0] = fmaf(a0, a0, lsq[0]); lsq[1] = fmaf(a1, a1, lsq[1]);
        lsq[2] = fmaf(a2, a2, lsq[2]); lsq[3] = fmaf(a3, a3, lsq[3]);
    }
    __syncthreads();   // sPh dead beyond here

    // ---------------- phase 7: BN partial sums
    #pragma unroll
    for (int q = 0; q < 4; q++) {
        sRa[ng * CC + c4 + q] = lsum[q];
        sRb[ng * CC + c4 + q] = lsq[q];
    }
    __syncthreads();
    if (t < CC) {
        float s = 0.0f, q2 = 0.0f;
        #pragma unroll
        for (int g = 0; g < 32; g++) {
            s  += sRa[g * CC + t];
            q2 += sRb[g * CC + t];
        }
        partial[(size_t)b * CC + t] = s;
        partialSq[(size_t)b * CC + t] = q2;
    }
}

// ------------------------------------------------------------- BN statistics
__global__ __launch_bounds__(256) void k_stats(
    const float* __restrict__ partial, const float* __restrict__ partialSq,
    const float* __restrict__ gamma, const float* __restrict__ beta,
    float* __restrict__ st)
{
    const int c = blockIdx.x, t = threadIdx.x;
    float s = 0.0f, q = 0.0f;
    for (int b = t; b < BB; b += 256) {
        s += partial[(size_t)b * CC + c];
        q += partialSq[(size_t)b * CC + c];
    }
    __shared__ float rs[256], rq[256];
    rs[t] = s; rq[t] = q;
    __syncthreads();
    for (int o = 128; o > 0; o >>= 1) {
        if (t < o) { rs[t] += rs[t + o]; rq[t] += rq[t + o]; }
        __syncthreads();
    }
    if (t == 0) {
        const float cntInv = 1.0f / (float)(BB * NN);
        float mean = rs[0] * cntInv;
        float var  = rq[0] * cntInv - mean * mean;
        float sc = gamma[c] * rsqrtf(var + 1e-5f);
        st[c] = sc;
        st[CC + c] = beta[c] - mean * sc;
    }
}

// ------------------------------------------------------------------- final
__global__ __launch_bounds__(256) void k_final(
    const float* __restrict__ pre, const float* __restrict__ st,
    const float* __restrict__ outW, const float* __restrict__ outb,
    float* __restrict__ out)
{
    __shared__ float sM[CC];
    __shared__ float sPart[4][CC];
    const int b = blockIdx.x, t = threadIdx.x;
    const int c = t & 63, p = t >> 6;
    const float* pv = pre + (size_t)b * (NN * CC);
    float s = st[c], sft = st[CC + c];
    float a = 0.0f;
    int nBeg = p * 23, nEnd = nBeg + 23 < NN ? nBeg + 23 : NN;
    for (int n = nBeg; n < nEnd; n++) {
        float v = fmaf(pv[n * CC + c], s, sft);
        a += (v > 0.0f ? v : 0.0f);
    }
    sPart[p][c] = a;
    __syncthreads();
    if (t < CC)
        sM[t] = (sPart[0][t] + sPart[1][t] + sPart[2][t] + sPart[3][t]) * (1.0f / (float)NN);
    __syncthreads();
    if (t < DOUT) {
        float acc = outb[t];
        #pragma unroll
        for (int cc2 = 0; cc2 < CC; cc2++) acc = fmaf(sM[cc2], outW[cc2 * DOUT + t], acc);
        out[(size_t)b * DOUT + t] = acc;
    }
}

// ------------------------------------------------------------------ launch
extern "C" void kernel_launch(void* const* d_in, const int* in_sizes, int n_in,
                              void* d_out, int out_size, void* d_ws, size_t ws_size,
                              hipStream_t stream) {
    (void)in_sizes; (void)n_in; (void)out_size; (void)ws_size;

    const float* bp   = (const float*)d_in[0];
    const float* inW  = (const float*)d_in[1];
    const float* inb  = (const float*)d_in[2];
    const float* W0   = (const float*)d_in[3];
    const float* as0  = (const float*)d_in[4];
    const float* ad0  = (const float*)d_in[5];
    const float* g0   = (const float*)d_in[6];
    const float* b0   = (const float*)d_in[7];
    const float* W1   = (const float*)d_in[8];
    const float* as1  = (const float*)d_in[9];
    const float* ad1  = (const float*)d_in[10];
    const float* g1   = (const float*)d_in[11];
    const float* b1   = (const float*)d_in[12];
    const float* outW = (const float*)d_in[13];
    const float* outb = (const float*)d_in[14];
    float* out = (float*)d_out;

    float* ws = (float*)d_ws;
    float* outPre    = ws;
    float* partial   = outPre + (size_t)BB * NN * CC;
    float* partialSq = partial + (size_t)BB * CC;
    float* st0       = partialSq + (size_t)BB * CC;
    float* st1       = st0 + 2 * CC;

    k_gat<0><<<BB, TPB, 0, stream>>>(bp, inW, inb, nullptr, nullptr,
                                     W0, as0, ad0, outPre, partial, partialSq);
    k_stats<<<CC, 256, 0, stream>>>(partial, partialSq, g0, b0, st0);
    k_gat<1><<<BB, TPB, 0, stream>>>(nullptr, nullptr, nullptr, outPre, st0,
                                     W1, as1, ad1, outPre, partial, partialSq);
    k_stats<<<CC, 256, 0, stream>>>(partial, partialSq, g1, b1, st1);
    k_final<<<BB, 256, 0, stream>>>(outPre, st1, outW, outb, out);
}